// Round 1
// baseline (810.386 us; speedup 1.0000x reference)
//
#include <hip/hip_runtime.h>

#define DEV __device__ __forceinline__

DEV float rlane(float v, int l) {
    return __int_as_float(__builtin_amdgcn_readlane(__float_as_int(v), l));
}
DEV float frcp(float x) { return __builtin_amdgcn_rcpf(x); }
DEV float ftanh(float x) { float e = __expf(2.0f * x); return 1.0f - 2.0f * frcp(e + 1.0f); }

constexpr int NN = 4096, TT = 128;

__global__ __launch_bounds__(256, 2) void wfa_kernel(
    const float* __restrict__ x,
    const float* __restrict__ e1w, const float* __restrict__ e1b,
    const float* __restrict__ e2w, const float* __restrict__ e2b,
    const float* __restrict__ A,
    const float* __restrict__ initw,
    const float* __restrict__ n1w, const float* __restrict__ n1b,
    const float* __restrict__ n2w, const float* __restrict__ n2b,
    const float* __restrict__ muw, const float* __restrict__ mub,
    const float* __restrict__ sgw, const float* __restrict__ sgb,
    const float* __restrict__ alw, const float* __restrict__ alb,
    float* __restrict__ out)
{
    // A in LDS as [i][j][d] (d innermost, 8 floats) -> per-lane float4 read is a
    // fully-coalesced 1KB wave read (BW floor, no conflict penalty).
    __shared__ __align__(16) float A_l[32 * 32 * 8];
    __shared__ __align__(16) float enc_l[4][TT * 8];   // per-wave encoder output
    __shared__ float x_l[4][TT];
    __shared__ float e1w_l[64], e1b_l[64];
    __shared__ __align__(16) float e2w_l[64 * 8];
    __shared__ float e2b_l[8];

    const int tid  = threadIdx.x;
    const int wv   = tid >> 6;
    const int lane = tid & 63;
    const int n    = blockIdx.x * 4 + wv;   // one wave = one sample

    // ---- stage block-shared data ----
    #pragma unroll
    for (int m = 0; m < 32; ++m) {
        int flat = m * 256 + tid;            // = i*256 + d*32 + j, i == m
        int d = (flat >> 5) & 7, j = flat & 31;
        A_l[(m * 32 + j) * 8 + d] = A[flat];
    }
    if (tid < 64) { e1w_l[tid] = e1w[tid]; e1b_l[tid] = e1b[tid]; }
    if (tid >= 64 && tid < 72) e2b_l[tid - 64] = e2b[tid - 64];
    for (int m = tid; m < 512; m += 256) e2w_l[m] = e2w[m];
    __syncthreads();

    // ---- per-lane weight columns in VGPRs ----
    float w1c[32];
    #pragma unroll
    for (int i = 0; i < 32; ++i) w1c[i] = n1w[i * 64 + lane];
    float w2c[64];
    #pragma unroll
    for (int i = 0; i < 64; ++i) w2c[i] = n2w[i * 64 + lane];
    const float b1c = n1b[lane], b2c = n2b[lane];

    // head columns: lanes 0-9 -> mu, 10-19 -> sig, 20-29 -> alpha
    float hwc[64];
    float hb = 0.0f;
    {
        const float* Wh = (lane < 10) ? muw : (lane < 20) ? sgw : alw;
        const int o = (lane < 10) ? lane : (lane < 20) ? lane - 10 : lane - 20;
        if (lane < 30) {
            #pragma unroll
            for (int i = 0; i < 64; ++i) hwc[i] = Wh[i * 10 + o];
            hb = (lane < 10) ? mub[o] : (lane < 20) ? sgb[o] : alb[o];
        } else {
            #pragma unroll
            for (int i = 0; i < 64; ++i) hwc[i] = 0.0f;
        }
    }

    // ---- load x; encoder (t on lanes: t = lane, lane+64) ----
    const float* xn = x + n * TT;
    const float xa = xn[lane], xb = xn[64 + lane];
    x_l[wv][lane] = xa; x_l[wv][64 + lane] = xb;

    #pragma unroll
    for (int half = 0; half < 2; ++half) {
        const float xt = half ? xb : xa;
        float acc[8];
        #pragma unroll
        for (int d = 0; d < 8; ++d) acc[d] = e2b_l[d];
        #pragma unroll 4
        for (int h = 0; h < 64; ++h) {
            const float e1 = fmaxf(fmaf(xt, e1w_l[h], e1b_l[h]), 0.0f);
            #pragma unroll
            for (int d = 0; d < 8; ++d) acc[d] = fmaf(e1, e2w_l[h * 8 + d], acc[d]);
        }
        const int t = lane + half * 64;
        #pragma unroll
        for (int d = 0; d < 8; ++d) enc_l[wv][t * 8 + d] = ftanh(acc[d]);
    }
    // each wave only reads its own enc_l/x_l rows -> no barrier needed

    const int j = lane & 31, dg = lane >> 5;
    float tmp = initw[j];        // replicated on lanes j and j+32
    float res = 0.0f;

    #pragma unroll 1
    for (int t = 0; t < TT; ++t) {
        if (t > 0) {
            // tmp_new[j] = sum_d e[d] * sum_i tmp[i] * A[i][d][j]
            float C0 = 0.f, C1 = 0.f, C2 = 0.f, C3 = 0.f;
            #pragma unroll
            for (int i = 0; i < 32; ++i) {
                const float4 a = *(const float4*)&A_l[i * 256 + j * 8 + dg * 4];
                const float ti = rlane(tmp, i);
                C0 = fmaf(ti, a.x, C0); C1 = fmaf(ti, a.y, C1);
                C2 = fmaf(ti, a.z, C2); C3 = fmaf(ti, a.w, C3);
            }
            const float4 e = *(const float4*)&enc_l[wv][(t - 1) * 8 + dg * 4];
            const float part = fmaf(C0, e.x, fmaf(C1, e.y, fmaf(C2, e.z, C3 * e.w)));
            tmp = part + __shfl_xor(part, 32, 64);
        }
        const float xt = x_l[wv][t];

        // phi: lane k owns hidden unit k
        const float th = ftanh(tmp);
        float a0 = b1c, a1 = 0.f, a2 = 0.f, a3 = 0.f;
        #pragma unroll
        for (int i = 0; i < 32; i += 4) {
            a0 = fmaf(rlane(th, i + 0), w1c[i + 0], a0);
            a1 = fmaf(rlane(th, i + 1), w1c[i + 1], a1);
            a2 = fmaf(rlane(th, i + 2), w1c[i + 2], a2);
            a3 = fmaf(rlane(th, i + 3), w1c[i + 3], a3);
        }
        const float h1 = fmaxf((a0 + a1) + (a2 + a3), 0.0f);

        a0 = b2c; a1 = 0.f; a2 = 0.f; a3 = 0.f;
        #pragma unroll
        for (int i = 0; i < 64; i += 4) {
            a0 = fmaf(rlane(h1, i + 0), w2c[i + 0], a0);
            a1 = fmaf(rlane(h1, i + 1), w2c[i + 1], a1);
            a2 = fmaf(rlane(h1, i + 2), w2c[i + 2], a2);
            a3 = fmaf(rlane(h1, i + 3), w2c[i + 3], a3);
        }
        const float h2 = fmaxf((a0 + a1) + (a2 + a3), 0.0f);

        a0 = hb; a1 = 0.f; a2 = 0.f; a3 = 0.f;
        #pragma unroll
        for (int i = 0; i < 64; i += 4) {
            a0 = fmaf(rlane(h2, i + 0), hwc[i + 0], a0);
            a1 = fmaf(rlane(h2, i + 1), hwc[i + 1], a1);
            a2 = fmaf(rlane(h2, i + 2), hwc[i + 2], a2);
            a3 = fmaf(rlane(h2, i + 3), hwc[i + 3], a3);
        }
        const float hd = (a0 + a1) + (a2 + a3);   // lane o<30: head value o

        // broadcast heads, replicated epilogue on all lanes
        float mu[10], sg[10], la[10];
        #pragma unroll
        for (int o = 0; o < 10; ++o) {
            mu[o] = rlane(hd, o);
            sg[o] = rlane(hd, 10 + o);
            la[o] = rlane(hd, 20 + o);
        }
        float m1 = la[0];
        #pragma unroll
        for (int o = 1; o < 10; ++o) m1 = fmaxf(m1, la[o]);
        float s1 = 0.f;
        #pragma unroll
        for (int o = 0; o < 10; ++o) s1 += __expf(la[o] - m1);
        const float lseA = m1 + __logf(s1);

        float tv[10];
        float m2 = -3.0e38f;
        #pragma unroll
        for (int o = 0; o < 10; ++o) {
            const float ei = __expf(-sg[o]);
            const float z = (xt - mu[o]) * ei;
            tv[o] = la[o] + fmaf(-0.5f * z, z, -sg[o] - 0.91893853320467274f);
            m2 = fmaxf(m2, tv[o]);
        }
        float s2 = 0.f;
        #pragma unroll
        for (int o = 0; o < 10; ++o) s2 += __expf(tv[o] - m2);
        res += (m2 + __logf(s2)) - lseA;
    }

    if (lane == 0) out[n] = __expf(res);
}

extern "C" void kernel_launch(void* const* d_in, const int* in_sizes, int n_in,
                              void* d_out, int out_size, void* d_ws, size_t ws_size,
                              hipStream_t stream) {
    wfa_kernel<<<dim3(NN / 4), dim3(256), 0, stream>>>(
        (const float*)d_in[0],  (const float*)d_in[1],  (const float*)d_in[2],
        (const float*)d_in[3],  (const float*)d_in[4],  (const float*)d_in[5],
        (const float*)d_in[6],  (const float*)d_in[7],  (const float*)d_in[8],
        (const float*)d_in[9],  (const float*)d_in[10], (const float*)d_in[11],
        (const float*)d_in[12], (const float*)d_in[13], (const float*)d_in[14],
        (const float*)d_in[15], (const float*)d_in[16], (float*)d_out);
}

// Round 2
// 806.730 us; speedup vs baseline: 1.0045x; 1.0045x over previous
//
#include <hip/hip_runtime.h>

#define DEV __device__ __forceinline__

DEV float rlane(float v, int l) {
    return __int_as_float(__builtin_amdgcn_readlane(__float_as_int(v), l));
}
DEV float frcp(float x) { return __builtin_amdgcn_rcpf(x); }
DEV float ftanh(float x) { float e = __expf(2.0f * x); return 1.0f - 2.0f * frcp(e + 1.0f); }

constexpr int NN = 4096, TT = 128;

__global__ __launch_bounds__(256, 2) void wfa_kernel(
    const float* __restrict__ x,
    const float* __restrict__ e1w, const float* __restrict__ e1b,
    const float* __restrict__ e2w, const float* __restrict__ e2b,
    const float* __restrict__ A,
    const float* __restrict__ initw,
    const float* __restrict__ n1w, const float* __restrict__ n1b,
    const float* __restrict__ n2w, const float* __restrict__ n2b,
    const float* __restrict__ muw, const float* __restrict__ mub,
    const float* __restrict__ sgw, const float* __restrict__ sgb,
    const float* __restrict__ alw, const float* __restrict__ alb,
    float* __restrict__ out)
{
    // A in LDS, float4-slot layout: slot s = i*64 + lane, where lane = dg*32 + j.
    // Slot s holds (A[i][dg*4+0][j], .., A[i][dg*4+3][j]). Per i-iteration the
    // wave reads slots i*64 .. i*64+63 with slot == lane -> each 16-lane phase
    // touches 256 consecutive bytes -> conflict-free. (R1 layout had dg as the
    // HIGH lane bit selecting even slots only -> 4-way phase conflicts, 6.9e7.)
    __shared__ __align__(16) float A_l[32 * 32 * 8];
    __shared__ __align__(16) float enc_l[4][TT * 8];   // per-wave encoder output
    __shared__ float x_l[4][TT];
    __shared__ float e1w_l[64], e1b_l[64];
    __shared__ __align__(16) float e2w_l[64 * 8];
    __shared__ float e2b_l[8];

    const int tid  = threadIdx.x;
    const int wv   = tid >> 6;
    const int lane = tid & 63;
    const int n    = blockIdx.x * 4 + wv;   // one wave = one sample

    // ---- stage block-shared data ----
    {
        const int d = tid >> 5, j = tid & 31;
        const int dst = (d >> 2) * 128 + j * 4 + (d & 3);  // transpose d into float4
        #pragma unroll
        for (int m = 0; m < 32; ++m) {
            A_l[m * 256 + dst] = A[m * 256 + tid];         // i = m
        }
    }
    if (tid < 64) { e1w_l[tid] = e1w[tid]; e1b_l[tid] = e1b[tid]; }
    if (tid >= 64 && tid < 72) e2b_l[tid - 64] = e2b[tid - 64];
    for (int m = tid; m < 512; m += 256) e2w_l[m] = e2w[m];
    __syncthreads();

    // ---- per-lane weight columns in VGPRs, PINNED so the compiler cannot
    // rematerialize them as per-step global reloads (R1: VGPR_Count=116 proved
    // the 160-float column set was being re-loaded inside the t-loop).
    float w1c[32];
    #pragma unroll
    for (int i = 0; i < 32; ++i) w1c[i] = n1w[i * 64 + lane];
    #pragma unroll
    for (int i = 0; i < 32; ++i) asm volatile("" : "+v"(w1c[i]));

    float w2c[64];
    #pragma unroll
    for (int i = 0; i < 64; ++i) w2c[i] = n2w[i * 64 + lane];
    #pragma unroll
    for (int i = 0; i < 64; ++i) asm volatile("" : "+v"(w2c[i]));

    const float b1c = n1b[lane], b2c = n2b[lane];

    // head columns: lanes 0-9 -> mu, 10-19 -> sig, 20-29 -> alpha
    float hwc[64];
    float hb = 0.0f;
    {
        const float* Wh = (lane < 10) ? muw : (lane < 20) ? sgw : alw;
        const int o = (lane < 10) ? lane : (lane < 20) ? lane - 10 : lane - 20;
        if (lane < 30) {
            #pragma unroll
            for (int i = 0; i < 64; ++i) hwc[i] = Wh[i * 10 + o];
            hb = (lane < 10) ? mub[o] : (lane < 20) ? sgb[o] : alb[o];
        } else {
            #pragma unroll
            for (int i = 0; i < 64; ++i) hwc[i] = 0.0f;
        }
    }
    #pragma unroll
    for (int i = 0; i < 64; ++i) asm volatile("" : "+v"(hwc[i]));

    // ---- load x; encoder (t on lanes: t = lane, lane+64) ----
    const float* xn = x + n * TT;
    const float xa = xn[lane], xb = xn[64 + lane];
    x_l[wv][lane] = xa; x_l[wv][64 + lane] = xb;

    #pragma unroll
    for (int half = 0; half < 2; ++half) {
        const float xt = half ? xb : xa;
        float acc[8];
        #pragma unroll
        for (int d = 0; d < 8; ++d) acc[d] = e2b_l[d];
        #pragma unroll 4
        for (int h = 0; h < 64; ++h) {
            const float e1 = fmaxf(fmaf(xt, e1w_l[h], e1b_l[h]), 0.0f);
            #pragma unroll
            for (int d = 0; d < 8; ++d) acc[d] = fmaf(e1, e2w_l[h * 8 + d], acc[d]);
        }
        const int t = lane + half * 64;
        #pragma unroll
        for (int d = 0; d < 8; ++d) enc_l[wv][t * 8 + d] = ftanh(acc[d]);
    }
    // each wave only reads its own enc_l/x_l rows -> no barrier needed

    const int dg = lane >> 5;
    float tmp = initw[lane & 31];   // replicated on lanes j and j+32
    float res = 0.0f;

    #pragma unroll 1
    for (int t = 0; t < TT; ++t) {
        if (t > 0) {
            // tmp_new[j] = sum_d e[d] * sum_i tmp[i] * A[i][d][j]
            float C0 = 0.f, C1 = 0.f, C2 = 0.f, C3 = 0.f;
            #pragma unroll
            for (int i = 0; i < 32; ++i) {
                const float4 a = *(const float4*)&A_l[i * 256 + lane * 4];
                const float ti = rlane(tmp, i);
                C0 = fmaf(ti, a.x, C0); C1 = fmaf(ti, a.y, C1);
                C2 = fmaf(ti, a.z, C2); C3 = fmaf(ti, a.w, C3);
            }
            const float4 e = *(const float4*)&enc_l[wv][(t - 1) * 8 + dg * 4];
            const float part = fmaf(C0, e.x, fmaf(C1, e.y, fmaf(C2, e.z, C3 * e.w)));
            tmp = part + __shfl_xor(part, 32, 64);
        }
        const float xt = x_l[wv][t];

        // phi: lane k owns hidden unit k
        const float th = ftanh(tmp);
        float a0 = b1c, a1 = 0.f, a2 = 0.f, a3 = 0.f;
        #pragma unroll
        for (int i = 0; i < 32; i += 4) {
            a0 = fmaf(rlane(th, i + 0), w1c[i + 0], a0);
            a1 = fmaf(rlane(th, i + 1), w1c[i + 1], a1);
            a2 = fmaf(rlane(th, i + 2), w1c[i + 2], a2);
            a3 = fmaf(rlane(th, i + 3), w1c[i + 3], a3);
        }
        const float h1 = fmaxf((a0 + a1) + (a2 + a3), 0.0f);

        a0 = b2c; a1 = 0.f; a2 = 0.f; a3 = 0.f;
        #pragma unroll
        for (int i = 0; i < 64; i += 4) {
            a0 = fmaf(rlane(h1, i + 0), w2c[i + 0], a0);
            a1 = fmaf(rlane(h1, i + 1), w2c[i + 1], a1);
            a2 = fmaf(rlane(h1, i + 2), w2c[i + 2], a2);
            a3 = fmaf(rlane(h1, i + 3), w2c[i + 3], a3);
        }
        const float h2 = fmaxf((a0 + a1) + (a2 + a3), 0.0f);

        a0 = hb; a1 = 0.f; a2 = 0.f; a3 = 0.f;
        #pragma unroll
        for (int i = 0; i < 64; i += 4) {
            a0 = fmaf(rlane(h2, i + 0), hwc[i + 0], a0);
            a1 = fmaf(rlane(h2, i + 1), hwc[i + 1], a1);
            a2 = fmaf(rlane(h2, i + 2), hwc[i + 2], a2);
            a3 = fmaf(rlane(h2, i + 3), hwc[i + 3], a3);
        }
        const float hd = (a0 + a1) + (a2 + a3);   // lane o<30: head value o

        // replicated epilogue; only tv[10] kept live (mu/sg/la re-read via
        // readlane to hold register pressure under the 256 cap)
        float m1 = rlane(hd, 20);
        #pragma unroll
        for (int o = 1; o < 10; ++o) m1 = fmaxf(m1, rlane(hd, 20 + o));
        float s1 = 0.f;
        #pragma unroll
        for (int o = 0; o < 10; ++o) s1 += __expf(rlane(hd, 20 + o) - m1);

        float tv[10];
        float m2 = -3.0e38f;
        #pragma unroll
        for (int o = 0; o < 10; ++o) {
            const float mu = rlane(hd, o);
            const float sg = rlane(hd, 10 + o);
            const float la = rlane(hd, 20 + o);
            const float ei = __expf(-sg);
            const float z = (xt - mu) * ei;
            tv[o] = (la - sg) + fmaf(-0.5f * z, z, -0.91893853320467274f);
            m2 = fmaxf(m2, tv[o]);
        }
        float s2 = 0.f;
        #pragma unroll
        for (int o = 0; o < 10; ++o) s2 += __expf(tv[o] - m2);
        res += (m2 + __logf(s2)) - (m1 + __logf(s1));
    }

    if (lane == 0) out[n] = __expf(res);
}

extern "C" void kernel_launch(void* const* d_in, const int* in_sizes, int n_in,
                              void* d_out, int out_size, void* d_ws, size_t ws_size,
                              hipStream_t stream) {
    wfa_kernel<<<dim3(NN / 4), dim3(256), 0, stream>>>(
        (const float*)d_in[0],  (const float*)d_in[1],  (const float*)d_in[2],
        (const float*)d_in[3],  (const float*)d_in[4],  (const float*)d_in[5],
        (const float*)d_in[6],  (const float*)d_in[7],  (const float*)d_in[8],
        (const float*)d_in[9],  (const float*)d_in[10], (const float*)d_in[11],
        (const float*)d_in[12], (const float*)d_in[13], (const float*)d_in[14],
        (const float*)d_in[15], (const float*)d_in[16], (float*)d_out);
}

// Round 3
// 391.295 us; speedup vs baseline: 2.0710x; 2.0617x over previous
//
#include <hip/hip_runtime.h>

#define DEV __device__ __forceinline__

typedef __attribute__((ext_vector_type(8))) short short8;
typedef __attribute__((ext_vector_type(4))) float f32x4;

DEV unsigned short bfr(float f) {                 // fp32 -> bf16 RNE
    unsigned u = __float_as_uint(f);
    return (unsigned short)((u + 0x7fffu + ((u >> 16) & 1u)) >> 16);
}
DEV float bf2f(unsigned short h) { return __uint_as_float(((unsigned)h) << 16); }
DEV float frcp(float x) { return __builtin_amdgcn_rcpf(x); }
DEV float ftanh(float x) { float e = __expf(2.0f * x); return 1.0f - 2.0f * frcp(e + 1.0f); }

constexpr int NN = 4096, TT = 128;
#define MFMA(a, b, c) __builtin_amdgcn_mfma_f32_16x16x32_bf16(a, b, c, 0, 0, 0)

// One wave per block; 16 samples per wave; M=16 rows = samples.
// Layouts (gfx950, verified in guide): A-frag A[m=lane&15][k=(lane>>4)*8+jj];
// B-frag B[k=(lane>>4)*8+jj][n=lane&15]; C/D: col=lane&15, row=(lane>>4)*4+reg.
__global__ __launch_bounds__(64, 1) void wfa_kernel(
    const float* __restrict__ x,
    const float* __restrict__ e1w, const float* __restrict__ e1b,
    const float* __restrict__ e2w, const float* __restrict__ e2b,
    const float* __restrict__ A,
    const float* __restrict__ initw,
    const float* __restrict__ n1w, const float* __restrict__ n1b,
    const float* __restrict__ n2w, const float* __restrict__ n2b,
    const float* __restrict__ muw, const float* __restrict__ mub,
    const float* __restrict__ sgw, const float* __restrict__ sgb,
    const float* __restrict__ alw, const float* __restrict__ alb,
    float* __restrict__ out)
{
    __shared__ __align__(16) unsigned short enc_l[TT * 128]; // [t][n*8+d] bf16
    __shared__ __align__(16) float x_l[16 * 130];            // [n][t], pad 130
    __shared__ __align__(16) float tmp_l[16 * 36];           // [n][j], pad 36
    __shared__ __align__(16) float h1_l[16 * 68];            // [n][h], pad 68
    __shared__ __align__(16) float h2_l[16 * 68];
    __shared__ __align__(16) float hd_l[16 * 36];            // [n][cc]

    const int lane = threadIdx.x;
    const int quad = lane >> 4, col = lane & 15;
    const int n0 = blockIdx.x * 16;
    const f32x4 z4 = {0.f, 0.f, 0.f, 0.f};

    // ---- stage x ----
    for (int i = lane; i < 16 * TT; i += 64)
        x_l[(i >> 7) * 130 + (i & 127)] = x[(n0 + (i >> 7)) * TT + (i & 127)];

    // ---- build weight B-fragments in VGPRs (reused 128 steps) ----
    short8 A2f[16];                       // contraction: B[k=i][16c+col] = A[i][c>>1][(c&1)*16+col]
    #pragma unroll
    for (int c = 0; c < 16; ++c)
        #pragma unroll
        for (int jj = 0; jj < 8; ++jj)
            A2f[c][jj] = (short)bfr(A[(quad * 8 + jj) * 256 + (c >> 1) * 32 + (c & 1) * 16 + col]);

    short8 W1f[4];
    #pragma unroll
    for (int nc = 0; nc < 4; ++nc)
        #pragma unroll
        for (int jj = 0; jj < 8; ++jj)
            W1f[nc][jj] = (short)bfr(n1w[(quad * 8 + jj) * 64 + nc * 16 + col]);

    short8 W2f[8];
    #pragma unroll
    for (int kb = 0; kb < 2; ++kb)
        #pragma unroll
        for (int nc = 0; nc < 4; ++nc)
            #pragma unroll
            for (int jj = 0; jj < 8; ++jj)
                W2f[kb * 4 + nc][jj] = (short)bfr(n2w[(kb * 32 + quad * 8 + jj) * 64 + nc * 16 + col]);

    short8 Whf[4];                        // packed heads: cols 0-9 mu, 10-19 sig, 20-29 alpha
    #pragma unroll
    for (int kb = 0; kb < 2; ++kb)
        #pragma unroll
        for (int nc = 0; nc < 2; ++nc) {
            const int cc = nc * 16 + col;
            #pragma unroll
            for (int jj = 0; jj < 8; ++jj) {
                const int k = kb * 32 + quad * 8 + jj;
                float v = 0.f;
                if (cc < 10) v = muw[k * 10 + cc];
                else if (cc < 20) v = sgw[k * 10 + cc - 10];
                else if (cc < 30) v = alw[k * 10 + cc - 20];
                Whf[kb * 2 + nc][jj] = (short)bfr(v);
            }
        }

    short8 E2f[2];
    #pragma unroll
    for (int kb = 0; kb < 2; ++kb)
        #pragma unroll
        for (int jj = 0; jj < 8; ++jj)
            E2f[kb][jj] = (short)bfr(col < 8 ? e2w[(kb * 32 + quad * 8 + jj) * 8 + col] : 0.f);

    short8 E1f[4];                        // rank-1 encoder layer: only k==0 nonzero
    #pragma unroll
    for (int nc = 0; nc < 4; ++nc)
        #pragma unroll
        for (int jj = 0; jj < 8; ++jj)
            E1f[nc][jj] = (short)((quad == 0 && jj == 0) ? bfr(e1w[nc * 16 + col]) : 0);

    float b1v[4], b2v[4], e1bv[4];
    #pragma unroll
    for (int nc = 0; nc < 4; ++nc) {
        b1v[nc] = n1b[nc * 16 + col];
        b2v[nc] = n2b[nc * 16 + col];
        e1bv[nc] = e1b[nc * 16 + col];
    }
    float hbv[2];
    #pragma unroll
    for (int nc = 0; nc < 2; ++nc) {
        const int cc = nc * 16 + col;
        hbv[nc] = (cc < 10) ? mub[cc] : (cc < 20) ? sgb[cc - 10] : (cc < 30) ? alb[cc - 20] : 0.f;
    }
    const float e2bv = (col < 8) ? e2b[col] : 0.f;

    __syncthreads();

    // ---- encoder: tiles of 16 t-rows; 2 sample-groups per iter for ILP ----
    #pragma unroll 1
    for (int tb = 0; tb < 8; ++tb) {
        #pragma unroll 1
        for (int nn = 0; nn < 8; ++nn) {
            const int nA = nn, nB = nn + 8;
            short8 a0, a1;
            #pragma unroll
            for (int jj = 0; jj < 8; ++jj) { a0[jj] = 0; a1[jj] = 0; }
            if (quad == 0) {
                a0[0] = (short)bfr(x_l[nA * 130 + tb * 16 + col]);
                a1[0] = (short)bfr(x_l[nB * 130 + tb * 16 + col]);
            }
            f32x4 c0[4], c1[4];
            #pragma unroll
            for (int nc = 0; nc < 4; ++nc) {
                c0[nc] = MFMA(a0, E1f[nc], z4);
                c1[nc] = MFMA(a1, E1f[nc], z4);
            }
            #pragma unroll
            for (int nc = 0; nc < 4; ++nc)
                #pragma unroll
                for (int reg = 0; reg < 4; ++reg) {
                    h1_l[(quad * 4 + reg) * 68 + nc * 16 + col] = fmaxf(c0[nc][reg] + e1bv[nc], 0.f);
                    h2_l[(quad * 4 + reg) * 68 + nc * 16 + col] = fmaxf(c1[nc][reg] + e1bv[nc], 0.f);
                }
            short8 af0[2], af1[2];
            #pragma unroll
            for (int kb = 0; kb < 2; ++kb) {
                const f32x4 lo0 = *(const f32x4*)&h1_l[col * 68 + kb * 32 + quad * 8];
                const f32x4 hi0 = *(const f32x4*)&h1_l[col * 68 + kb * 32 + quad * 8 + 4];
                const f32x4 lo1 = *(const f32x4*)&h2_l[col * 68 + kb * 32 + quad * 8];
                const f32x4 hi1 = *(const f32x4*)&h2_l[col * 68 + kb * 32 + quad * 8 + 4];
                #pragma unroll
                for (int jj = 0; jj < 4; ++jj) {
                    af0[kb][jj] = (short)bfr(lo0[jj]); af0[kb][jj + 4] = (short)bfr(hi0[jj]);
                    af1[kb][jj] = (short)bfr(lo1[jj]); af1[kb][jj + 4] = (short)bfr(hi1[jj]);
                }
            }
            f32x4 d0 = MFMA(af0[0], E2f[0], z4); d0 = MFMA(af0[1], E2f[1], d0);
            f32x4 d1 = MFMA(af1[0], E2f[0], z4); d1 = MFMA(af1[1], E2f[1], d1);
            if (col < 8) {
                #pragma unroll
                for (int reg = 0; reg < 4; ++reg) {
                    const int t = tb * 16 + quad * 4 + reg;
                    enc_l[t * 128 + nA * 8 + col] = bfr(ftanh(d0[reg] + e2bv));
                    enc_l[t * 128 + nB * 8 + col] = bfr(ftanh(d1[reg] + e2bv));
                }
            }
        }
    }

    // ---- recurrence ----
    short8 tmpf, thf;
    #pragma unroll
    for (int jj = 0; jj < 8; ++jj) {
        const float v = initw[quad * 8 + jj];
        tmpf[jj] = (short)bfr(v);
        thf[jj]  = (short)bfr(ftanh(v));
    }
    float res = 0.f;
    const int en = lane >> 2, er = lane & 3;
    const float CST = 0.91893853320467274f;

    #pragma unroll 1
    for (int t = 0; t < TT; ++t) {
        if (t > 0) {
            // v[n][dj] = sum_i tmp[n][i] * A[i][d][j]  (16 MFMAs)
            f32x4 vc[16];
            #pragma unroll
            for (int c = 0; c < 16; ++c) vc[c] = MFMA(tmpf, A2f[c], z4);
            // tmp_new[n][j] = sum_d e[n][d] * v[n][d*32+j]
            #pragma unroll
            for (int reg = 0; reg < 4; ++reg) {
                const short8 e8 = *(const short8*)&enc_l[(t - 1) * 128 + (quad * 4 + reg) * 8];
                float ev[8];
                #pragma unroll
                for (int d = 0; d < 8; ++d) ev[d] = bf2f((unsigned short)e8[d]);
                #pragma unroll
                for (int h = 0; h < 2; ++h) {
                    float s = 0.f;
                    #pragma unroll
                    for (int d = 0; d < 8; ++d) s = fmaf(ev[d], vc[2 * d + h][reg], s);
                    tmp_l[(quad * 4 + reg) * 36 + h * 16 + col] = s;
                }
            }
            // round trip -> A-frag for next contraction + tanh for phi
            const f32x4 lo = *(const f32x4*)&tmp_l[col * 36 + quad * 8];
            const f32x4 hi = *(const f32x4*)&tmp_l[col * 36 + quad * 8 + 4];
            #pragma unroll
            for (int jj = 0; jj < 4; ++jj) {
                tmpf[jj]     = (short)bfr(lo[jj]);   thf[jj]     = (short)bfr(ftanh(lo[jj]));
                tmpf[jj + 4] = (short)bfr(hi[jj]);   thf[jj + 4] = (short)bfr(ftanh(hi[jj]));
            }
        }
        // h1 = relu(th @ W1 + b1)
        f32x4 hc[4];
        #pragma unroll
        for (int nc = 0; nc < 4; ++nc) hc[nc] = MFMA(thf, W1f[nc], z4);
        #pragma unroll
        for (int nc = 0; nc < 4; ++nc)
            #pragma unroll
            for (int reg = 0; reg < 4; ++reg)
                h1_l[(quad * 4 + reg) * 68 + nc * 16 + col] = fmaxf(hc[nc][reg] + b1v[nc], 0.f);
        short8 h1f[2];
        #pragma unroll
        for (int kb = 0; kb < 2; ++kb) {
            const f32x4 lo = *(const f32x4*)&h1_l[col * 68 + kb * 32 + quad * 8];
            const f32x4 hi = *(const f32x4*)&h1_l[col * 68 + kb * 32 + quad * 8 + 4];
            #pragma unroll
            for (int jj = 0; jj < 4; ++jj) {
                h1f[kb][jj] = (short)bfr(lo[jj]); h1f[kb][jj + 4] = (short)bfr(hi[jj]);
            }
        }
        // h2 = relu(h1 @ W2 + b2)
        #pragma unroll
        for (int nc = 0; nc < 4; ++nc) {
            f32x4 d = MFMA(h1f[0], W2f[nc], z4);
            hc[nc] = MFMA(h1f[1], W2f[4 + nc], d);
        }
        #pragma unroll
        for (int nc = 0; nc < 4; ++nc)
            #pragma unroll
            for (int reg = 0; reg < 4; ++reg)
                h2_l[(quad * 4 + reg) * 68 + nc * 16 + col] = fmaxf(hc[nc][reg] + b2v[nc], 0.f);
        short8 h2f[2];
        #pragma unroll
        for (int kb = 0; kb < 2; ++kb) {
            const f32x4 lo = *(const f32x4*)&h2_l[col * 68 + kb * 32 + quad * 8];
            const f32x4 hi = *(const f32x4*)&h2_l[col * 68 + kb * 32 + quad * 8 + 4];
            #pragma unroll
            for (int jj = 0; jj < 4; ++jj) {
                h2f[kb][jj] = (short)bfr(lo[jj]); h2f[kb][jj + 4] = (short)bfr(hi[jj]);
            }
        }
        // heads
        #pragma unroll
        for (int nc = 0; nc < 2; ++nc) {
            f32x4 d = MFMA(h2f[0], Whf[nc], z4);
            d = MFMA(h2f[1], Whf[2 + nc], d);
            #pragma unroll
            for (int reg = 0; reg < 4; ++reg)
                hd_l[(quad * 4 + reg) * 36 + nc * 16 + col] = d[reg] + hbv[nc];
        }
        // epilogue: lane = (sample en, replica er); comps k = er, er+4, er+8(<10)
        const float xt = x_l[en * 130 + t];
        const float mu0 = hd_l[en * 36 + er],      sg0 = hd_l[en * 36 + 10 + er], la0 = hd_l[en * 36 + 20 + er];
        const float mu1 = hd_l[en * 36 + 4 + er],  sg1 = hd_l[en * 36 + 14 + er], la1 = hd_l[en * 36 + 24 + er];
        const bool has2 = (er < 2);
        const float mu2 = has2 ? hd_l[en * 36 + 8 + er]  : 0.f;
        const float sg2 = has2 ? hd_l[en * 36 + 18 + er] : 0.f;
        const float la2 = has2 ? hd_l[en * 36 + 28 + er] : -1e30f;

        float M1 = fmaxf(fmaxf(la0, la1), la2);
        M1 = fmaxf(M1, __shfl_xor(M1, 1, 64));
        M1 = fmaxf(M1, __shfl_xor(M1, 2, 64));
        float s1 = __expf(la0 - M1) + __expf(la1 - M1) + __expf(la2 - M1);
        s1 += __shfl_xor(s1, 1, 64);
        s1 += __shfl_xor(s1, 2, 64);
        const float lseA = M1 + __logf(s1);

        float z0 = (xt - mu0) * __expf(-sg0);
        float z1 = (xt - mu1) * __expf(-sg1);
        const float tv0 = la0 - sg0 - fmaf(0.5f * z0, z0, CST);
        const float tv1 = la1 - sg1 - fmaf(0.5f * z1, z1, CST);
        float tv2 = -1e30f;
        if (has2) {
            float z2 = (xt - mu2) * __expf(-sg2);
            tv2 = la2 - sg2 - fmaf(0.5f * z2, z2, CST);
        }
        float M2 = fmaxf(fmaxf(tv0, tv1), tv2);
        M2 = fmaxf(M2, __shfl_xor(M2, 1, 64));
        M2 = fmaxf(M2, __shfl_xor(M2, 2, 64));
        float s2 = __expf(tv0 - M2) + __expf(tv1 - M2) + __expf(tv2 - M2);
        s2 += __shfl_xor(s2, 1, 64);
        s2 += __shfl_xor(s2, 2, 64);
        res += (M2 + __logf(s2)) - lseA;
    }

    if ((lane & 3) == 0) out[n0 + en] = __expf(res);
}

extern "C" void kernel_launch(void* const* d_in, const int* in_sizes, int n_in,
                              void* d_out, int out_size, void* d_ws, size_t ws_size,
                              hipStream_t stream) {
    wfa_kernel<<<dim3(NN / 16), dim3(64), 0, stream>>>(
        (const float*)d_in[0],  (const float*)d_in[1],  (const float*)d_in[2],
        (const float*)d_in[3],  (const float*)d_in[4],  (const float*)d_in[5],
        (const float*)d_in[6],  (const float*)d_in[7],  (const float*)d_in[8],
        (const float*)d_in[9],  (const float*)d_in[10], (const float*)d_in[11],
        (const float*)d_in[12], (const float*)d_in[13], (const float*)d_in[14],
        (const float*)d_in[15], (const float*)d_in[16], (float*)d_out);
}

// Round 4
// 185.836 us; speedup vs baseline: 4.3608x; 2.1056x over previous
//
#include <hip/hip_runtime.h>

#define DEV __device__ __forceinline__

typedef __attribute__((ext_vector_type(8))) short short8;
typedef __attribute__((ext_vector_type(4))) float f32x4;

DEV unsigned short bfr(float f) {                 // fp32 -> bf16 RNE (weights, one-time)
    unsigned u = __float_as_uint(f);
    return (unsigned short)((u + 0x7fffu + ((u >> 16) & 1u)) >> 16);
}
DEV short bft(float f) { return (short)(__float_as_uint(f) >> 16); } // truncate (activations)
DEV float bf2f(unsigned short h) { return __uint_as_float(((unsigned)h) << 16); }
DEV float frcp(float x) { return __builtin_amdgcn_rcpf(x); }
DEV float ftanh(float x) { float e = __expf(2.0f * x); return 1.0f - 2.0f * frcp(e + 1.0f); }

constexpr int NN = 4096, TT = 128;
#define MFMA(a, b, c) __builtin_amdgcn_mfma_f32_16x16x32_bf16(a, b, c, 0, 0, 0)

// 8 waves/block, 16 samples/block. Wave w owns t-chunk [CH_S[w], CH_S[w]+CH_L[w]):
// re-propagates tmp cheaply (linear recurrence, no phi) to its chunk start, then
// does full phi steps only inside its chunk. Lengths graded so
// prefix*cheap_cost + len*full_cost is ~equal across waves.
__constant__ const int CH_S[8] = {0, 28, 52, 72, 89, 103, 114, 122};
__constant__ const int CH_L[8] = {28, 24, 20, 17, 14, 11, 8, 6};

__global__ __launch_bounds__(512, 2) void wfa_kernel(
    const float* __restrict__ x,
    const float* __restrict__ e1w, const float* __restrict__ e1b,
    const float* __restrict__ e2w, const float* __restrict__ e2b,
    const float* __restrict__ A,
    const float* __restrict__ initw,
    const float* __restrict__ n1w, const float* __restrict__ n1b,
    const float* __restrict__ n2w, const float* __restrict__ n2b,
    const float* __restrict__ muw, const float* __restrict__ mub,
    const float* __restrict__ sgw, const float* __restrict__ sgb,
    const float* __restrict__ alw, const float* __restrict__ alb,
    float* __restrict__ out)
{
    __shared__ __align__(16) unsigned short enc_l[TT * 128];  // [t][n*8+d] bf16, 32KB
    __shared__ __align__(16) float x_l[16 * 130];             // [n][t]
    __shared__ __align__(16) float tmp_l[8][16 * 36];         // per-wave [n][j]
    __shared__ __align__(16) float hs_l[8][16 * 68];          // per-wave h1/h2 scratch
    __shared__ __align__(16) float hd_l[8][16 * 36];          // per-wave head scratch
    __shared__ float part_l[8][16];                           // per-wave res partials

    const int tid = threadIdx.x;
    const int wv = tid >> 6, lane = tid & 63;
    const int quad = lane >> 4, col = lane & 15;
    const int n0 = blockIdx.x * 16;
    const f32x4 z4 = {0.f, 0.f, 0.f, 0.f};

    float* tmpw = tmp_l[wv];
    float* hsw  = hs_l[wv];
    float* hdw  = hd_l[wv];

    // ---- stage x ----
    for (int i = tid; i < 16 * TT; i += 512)
        x_l[(i >> 7) * 130 + (i & 127)] = x[(n0 + (i >> 7)) * TT + (i & 127)];

    // ---- persistent weight B-fragments (every wave builds its own copy) ----
    short8 A2f[16];   // B[k=i][16c+col] = A[i][c>>1][(c&1)*16+col]
    #pragma unroll
    for (int c = 0; c < 16; ++c)
        #pragma unroll
        for (int jj = 0; jj < 8; ++jj)
            A2f[c][jj] = (short)bfr(A[(quad * 8 + jj) * 256 + (c >> 1) * 32 + (c & 1) * 16 + col]);

    short8 W1f[4];
    #pragma unroll
    for (int nc = 0; nc < 4; ++nc)
        #pragma unroll
        for (int jj = 0; jj < 8; ++jj)
            W1f[nc][jj] = (short)bfr(n1w[(quad * 8 + jj) * 64 + nc * 16 + col]);

    short8 W2f[8];
    #pragma unroll
    for (int kb = 0; kb < 2; ++kb)
        #pragma unroll
        for (int nc = 0; nc < 4; ++nc)
            #pragma unroll
            for (int jj = 0; jj < 8; ++jj)
                W2f[kb * 4 + nc][jj] = (short)bfr(n2w[(kb * 32 + quad * 8 + jj) * 64 + nc * 16 + col]);

    short8 Whf[4];    // cols 0-9 mu, 10-19 sig, 20-29 alpha
    #pragma unroll
    for (int kb = 0; kb < 2; ++kb)
        #pragma unroll
        for (int nc = 0; nc < 2; ++nc) {
            const int cc = nc * 16 + col;
            #pragma unroll
            for (int jj = 0; jj < 8; ++jj) {
                const int k = kb * 32 + quad * 8 + jj;
                float v = 0.f;
                if (cc < 10) v = muw[k * 10 + cc];
                else if (cc < 20) v = sgw[k * 10 + cc - 10];
                else if (cc < 30) v = alw[k * 10 + cc - 20];
                Whf[kb * 2 + nc][jj] = (short)bfr(v);
            }
        }

    float b1v[4], b2v[4];
    #pragma unroll
    for (int nc = 0; nc < 4; ++nc) { b1v[nc] = n1b[nc * 16 + col]; b2v[nc] = n2b[nc * 16 + col]; }
    float hbv[2];
    #pragma unroll
    for (int nc = 0; nc < 2; ++nc) {
        const int cc = nc * 16 + col;
        hbv[nc] = (cc < 10) ? mub[cc] : (cc < 20) ? sgb[cc - 10] : (cc < 30) ? alb[cc - 20] : 0.f;
    }

    // ---- encoder: wave w computes t-tile tb=w (frags scoped so regs die) ----
    {
        short8 E2f[2];
        #pragma unroll
        for (int kb = 0; kb < 2; ++kb)
            #pragma unroll
            for (int jj = 0; jj < 8; ++jj)
                E2f[kb][jj] = (short)bfr(col < 8 ? e2w[(kb * 32 + quad * 8 + jj) * 8 + col] : 0.f);
        short8 E1f[4];   // rank-1 layer: only k==0 nonzero
        #pragma unroll
        for (int nc = 0; nc < 4; ++nc)
            #pragma unroll
            for (int jj = 0; jj < 8; ++jj)
                E1f[nc][jj] = (short)((quad == 0 && jj == 0) ? bfr(e1w[nc * 16 + col]) : 0);
        float e1bv[4];
        #pragma unroll
        for (int nc = 0; nc < 4; ++nc) e1bv[nc] = e1b[nc * 16 + col];
        const float e2bv = (col < 8) ? e2b[col] : 0.f;

        __syncthreads();   // x_l ready

        #pragma unroll 1
        for (int nn = 0; nn < 16; ++nn) {
            short8 a0;
            #pragma unroll
            for (int jj = 0; jj < 8; ++jj) a0[jj] = 0;
            if (quad == 0) a0[0] = (short)bfr(x_l[nn * 130 + wv * 16 + col]);
            f32x4 c0[4];
            #pragma unroll
            for (int nc = 0; nc < 4; ++nc) c0[nc] = MFMA(a0, E1f[nc], z4);
            #pragma unroll
            for (int nc = 0; nc < 4; ++nc)
                #pragma unroll
                for (int reg = 0; reg < 4; ++reg)
                    hsw[(quad * 4 + reg) * 68 + nc * 16 + col] = fmaxf(c0[nc][reg] + e1bv[nc], 0.f);
            short8 af[2];
            #pragma unroll
            for (int kb = 0; kb < 2; ++kb) {
                const f32x4 lo = *(const f32x4*)&hsw[col * 68 + kb * 32 + quad * 8];
                const f32x4 hi = *(const f32x4*)&hsw[col * 68 + kb * 32 + quad * 8 + 4];
                #pragma unroll
                for (int jj = 0; jj < 4; ++jj) { af[kb][jj] = bft(lo[jj]); af[kb][jj + 4] = bft(hi[jj]); }
            }
            f32x4 d0 = MFMA(af[0], E2f[0], z4);
            d0 = MFMA(af[1], E2f[1], d0);
            if (col < 8) {
                #pragma unroll
                for (int reg = 0; reg < 4; ++reg)
                    enc_l[(wv * 16 + quad * 4 + reg) * 128 + nn * 8 + col] = bfr(ftanh(d0[reg] + e2bv));
            }
        }
    }
    __syncthreads();   // enc_l fully ready

    // ---- recurrence ----
    short8 tmpf, thf;
    #pragma unroll
    for (int jj = 0; jj < 8; ++jj) {
        const float v = initw[quad * 8 + jj];
        tmpf[jj] = (short)bfr(v);
        thf[jj]  = (short)bfr(ftanh(v));
    }
    float res2 = 0.f;
    const int en = lane >> 2, er = lane & 3;
    const bool has2 = (er < 2);
    const float CST = 0.91893853320467274f;
    const int t0 = CH_S[wv], CL = CH_L[wv];

    // advance: tmp_{t} from tmp_{t-1} using enc[t-1]; optional tanh for phi
    auto advance = [&](int t, bool wantth) {
        short8 e8[4];
        #pragma unroll
        for (int reg = 0; reg < 4; ++reg)
            e8[reg] = *(const short8*)&enc_l[(t - 1) * 128 + (quad * 4 + reg) * 8];
        #pragma unroll
        for (int h = 0; h < 2; ++h) {       // j-half; halves vc register pressure
            f32x4 vc[8];
            #pragma unroll
            for (int d = 0; d < 8; ++d) vc[d] = MFMA(tmpf, A2f[2 * d + h], z4);
            #pragma unroll
            for (int reg = 0; reg < 4; ++reg) {
                float s = 0.f;
                #pragma unroll
                for (int d = 0; d < 8; ++d)
                    s = fmaf(bf2f((unsigned short)e8[reg][d]), vc[d][reg], s);
                tmpw[(quad * 4 + reg) * 36 + h * 16 + col] = s;
            }
        }
        const f32x4 lo = *(const f32x4*)&tmpw[col * 36 + quad * 8];
        const f32x4 hi = *(const f32x4*)&tmpw[col * 36 + quad * 8 + 4];
        #pragma unroll
        for (int jj = 0; jj < 4; ++jj) { tmpf[jj] = bft(lo[jj]); tmpf[jj + 4] = bft(hi[jj]); }
        if (wantth) {
            #pragma unroll
            for (int jj = 0; jj < 4; ++jj) {
                thf[jj]     = bft(ftanh(lo[jj]));
                thf[jj + 4] = bft(ftanh(hi[jj]));
            }
        }
    };

    // cheap prefix: propagate tmp to this wave's chunk start
    #pragma unroll 1
    for (int t = 1; t <= t0; ++t) advance(t, t == t0);

    // full steps inside the chunk
    #pragma unroll 1
    for (int s = 0; s < CL; ++s) {
        const int t = t0 + s;
        if (s > 0) advance(t, true);

        // h1 = relu(th @ W1 + b1)
        f32x4 hc[4];
        #pragma unroll
        for (int nc = 0; nc < 4; ++nc) hc[nc] = MFMA(thf, W1f[nc], z4);
        #pragma unroll
        for (int nc = 0; nc < 4; ++nc)
            #pragma unroll
            for (int reg = 0; reg < 4; ++reg)
                hsw[(quad * 4 + reg) * 68 + nc * 16 + col] = fmaxf(hc[nc][reg] + b1v[nc], 0.f);
        short8 h1f[2];
        #pragma unroll
        for (int kb = 0; kb < 2; ++kb) {
            const f32x4 lo = *(const f32x4*)&hsw[col * 68 + kb * 32 + quad * 8];
            const f32x4 hi = *(const f32x4*)&hsw[col * 68 + kb * 32 + quad * 8 + 4];
            #pragma unroll
            for (int jj = 0; jj < 4; ++jj) { h1f[kb][jj] = bft(lo[jj]); h1f[kb][jj + 4] = bft(hi[jj]); }
        }
        // h2 = relu(h1 @ W2 + b2) (same scratch buffer; DS pipe is in-order per wave)
        #pragma unroll
        for (int nc = 0; nc < 4; ++nc) {
            f32x4 d = MFMA(h1f[0], W2f[nc], z4);
            hc[nc] = MFMA(h1f[1], W2f[4 + nc], d);
        }
        #pragma unroll
        for (int nc = 0; nc < 4; ++nc)
            #pragma unroll
            for (int reg = 0; reg < 4; ++reg)
                hsw[(quad * 4 + reg) * 68 + nc * 16 + col] = fmaxf(hc[nc][reg] + b2v[nc], 0.f);
        short8 h2f[2];
        #pragma unroll
        for (int kb = 0; kb < 2; ++kb) {
            const f32x4 lo = *(const f32x4*)&hsw[col * 68 + kb * 32 + quad * 8];
            const f32x4 hi = *(const f32x4*)&hsw[col * 68 + kb * 32 + quad * 8 + 4];
            #pragma unroll
            for (int jj = 0; jj < 4; ++jj) { h2f[kb][jj] = bft(lo[jj]); h2f[kb][jj + 4] = bft(hi[jj]); }
        }
        // heads
        #pragma unroll
        for (int nc = 0; nc < 2; ++nc) {
            f32x4 d = MFMA(h2f[0], Whf[nc], z4);
            d = MFMA(h2f[1], Whf[2 + nc], d);
            #pragma unroll
            for (int reg = 0; reg < 4; ++reg)
                hdw[(quad * 4 + reg) * 36 + nc * 16 + col] = d[reg] + hbv[nc];
        }
        // epilogue, no-max logsumexp (tv <= la = O(1): no overflow; underflow ->
        // -inf -> exp2 -> 0, which equals the reference's underflowed-to-0 output)
        const float xt = x_l[en * 130 + t];
        const float mu0 = hdw[en * 36 + er],     sg0 = hdw[en * 36 + 10 + er], la0 = hdw[en * 36 + 20 + er];
        const float mu1 = hdw[en * 36 + 4 + er], sg1 = hdw[en * 36 + 14 + er], la1 = hdw[en * 36 + 24 + er];
        const float mu2 = has2 ? hdw[en * 36 + 8 + er]  : 0.f;
        const float sg2 = has2 ? hdw[en * 36 + 18 + er] : 0.f;
        const float la2 = has2 ? hdw[en * 36 + 28 + er] : 0.f;

        float s1 = __expf(la0) + __expf(la1) + (has2 ? __expf(la2) : 0.f);

        const float z0 = (xt - mu0) * __expf(-sg0);
        const float z1 = (xt - mu1) * __expf(-sg1);
        const float tv0 = la0 - sg0 - fmaf(0.5f * z0, z0, CST);
        const float tv1 = la1 - sg1 - fmaf(0.5f * z1, z1, CST);
        float s2 = __expf(tv0) + __expf(tv1);
        if (has2) {
            const float z2 = (xt - mu2) * __expf(-sg2);
            s2 += __expf(la2 - sg2 - fmaf(0.5f * z2, z2, CST));
        }
        s1 += __shfl_xor(s1, 1, 64);  s2 += __shfl_xor(s2, 1, 64);
        s1 += __shfl_xor(s1, 2, 64);  s2 += __shfl_xor(s2, 2, 64);
        res2 += __log2f(s2) - __log2f(s1);
    }

    if (er == 0) part_l[wv][en] = res2;
    __syncthreads();
    if (tid < 16) {
        float s = 0.f;
        #pragma unroll
        for (int w = 0; w < 8; ++w) s += part_l[w][tid];
        out[n0 + tid] = exp2f(s);
    }
}

extern "C" void kernel_launch(void* const* d_in, const int* in_sizes, int n_in,
                              void* d_out, int out_size, void* d_ws, size_t ws_size,
                              hipStream_t stream) {
    wfa_kernel<<<dim3(NN / 16), dim3(512), 0, stream>>>(
        (const float*)d_in[0],  (const float*)d_in[1],  (const float*)d_in[2],
        (const float*)d_in[3],  (const float*)d_in[4],  (const float*)d_in[5],
        (const float*)d_in[6],  (const float*)d_in[7],  (const float*)d_in[8],
        (const float*)d_in[9],  (const float*)d_in[10], (const float*)d_in[11],
        (const float*)d_in[12], (const float*)d_in[13], (const float*)d_in[14],
        (const float*)d_in[15], (const float*)d_in[16], (float*)d_out);
}